// Round 1
// baseline (259.180 us; speedup 1.0000x reference)
//
#include <hip/hip_runtime.h>

#define ECE_N_BINS 15

// Zero the 30-float accumulator in d_ws (harness poisons it with 0xAA and
// does NOT re-poison between replays, so we must clear it every call).
__global__ void ece_zero_ws(float* __restrict__ ws) {
    int t = threadIdx.x;
    if (t < 2 * ECE_N_BINS) ws[t] = 0.0f;
}

// Main pass: per-row max + argmax over C=128, bin by confidence, accumulate
// sum_conf / sum_acc per bin. One 64-lane wave processes 2 rows per iter:
// lanes 0-31 -> row 2p, lanes 32-63 -> row 2p+1; each lane loads float4 at
// column (lane&31)*4 -> the wave reads 1024 contiguous bytes (coalesced).
__global__ __launch_bounds__(256) void ece_main(const float* __restrict__ sm,
                                                const int* __restrict__ labels,
                                                float* __restrict__ ws,
                                                int N) {
    __shared__ float s_conf[ECE_N_BINS];
    __shared__ float s_acc[ECE_N_BINS];

    const int t = threadIdx.x;
    if (t < ECE_N_BINS) { s_conf[t] = 0.0f; s_acc[t] = 0.0f; }
    __syncthreads();

    const int lane = t & 63;
    const int half = lane >> 5;      // which row of the pair
    const int s    = lane & 31;      // sublane within the row
    const int wavesPerBlock = blockDim.x >> 6;
    const long long waveId  = (long long)blockIdx.x * wavesPerBlock + (t >> 6);
    const long long nWaves  = (long long)gridDim.x * wavesPerBlock;
    const long long nPairs  = (long long)(N + 1) / 2;

    for (long long pair = waveId; pair < nPairs; pair += nWaves) {
        const long long row = pair * 2 + half;
        if (row < N) {
            const float4 v =
                *reinterpret_cast<const float4*>(sm + row * 128 + s * 4);
            // local max/argmax among this lane's 4 elements (first-index wins)
            float m = v.x; int idx = s * 4;
            if (v.y > m) { m = v.y; idx = s * 4 + 1; }
            if (v.z > m) { m = v.z; idx = s * 4 + 2; }
            if (v.w > m) { m = v.w; idx = s * 4 + 3; }
            // butterfly across the 32 lanes of this half (xor<32 stays in half)
            #pragma unroll
            for (int off = 1; off < 32; off <<= 1) {
                float om = __shfl_xor(m, off);
                int   oi = __shfl_xor(idx, off);
                if (om > m || (om == m && oi < idx)) { m = om; idx = oi; }
            }
            if (s == 0) {
                // bin i covers (i/15, (i+1)/15]; ceil-based index, clamped
                int b = (int)ceilf(m * 15.0f) - 1;
                b = min(max(b, 0), ECE_N_BINS - 1);
                const float acc = (labels[row] == idx) ? 1.0f : 0.0f;
                atomicAdd(&s_conf[b], m);
                atomicAdd(&s_acc[b], acc);
            }
        }
    }

    __syncthreads();
    if (t < ECE_N_BINS) {
        atomicAdd(&ws[t],              s_conf[t]);
        atomicAdd(&ws[ECE_N_BINS + t], s_acc[t]);
    }
}

// Final: ece = sum_bins |sum_conf - sum_acc| / N
__global__ void ece_final(const float* __restrict__ ws,
                          float* __restrict__ out, int N) {
    if (threadIdx.x == 0 && blockIdx.x == 0) {
        float e = 0.0f;
        #pragma unroll
        for (int i = 0; i < ECE_N_BINS; ++i)
            e += fabsf(ws[i] - ws[ECE_N_BINS + i]);
        out[0] = e / (float)N;
    }
}

extern "C" void kernel_launch(void* const* d_in, const int* in_sizes, int n_in,
                              void* d_out, int out_size, void* d_ws, size_t ws_size,
                              hipStream_t stream) {
    const float* sm     = (const float*)d_in[0];
    const int*   labels = (const int*)d_in[1];
    float*       out    = (float*)d_out;
    float*       ws     = (float*)d_ws;

    const int N = in_sizes[0] / 128;   // rows; in_sizes[1] == N as well

    ece_zero_ws<<<1, 64, 0, stream>>>(ws);

    const int block = 256;              // 4 waves -> 8 rows per block-iter
    const int grid  = 2048;             // 256 CUs x 8 blocks, grid-stride
    ece_main<<<grid, block, 0, stream>>>(sm, labels, ws, N);

    ece_final<<<1, 64, 0, stream>>>(ws, out, N);
}

// Round 3
// 205.413 us; speedup vs baseline: 1.2617x; 1.2617x over previous
//
#include <hip/hip_runtime.h>

#define ECE_N_BINS 15

typedef float f32x4 __attribute__((ext_vector_type(4)));

// Zero the 30-float accumulator in d_ws (harness poisons once, never re-poisons).
__global__ void ece_zero_ws(float* __restrict__ ws) {
    int t = threadIdx.x;
    if (t < 2 * ECE_N_BINS) ws[t] = 0.0f;
}

// Main pass. One 64-lane wave owns 8 consecutive rows (4 KB) per iteration:
// lanes 0-31 -> even rows, lanes 32-63 -> odd rows; each lane issues 4
// independent float4 loads (rows pair+0,2,4,6) for 4x memory-level
// parallelism, then runs 4 interleaved max/argmax butterflies.
__global__ __launch_bounds__(256) void ece_main(const float* __restrict__ sm,
                                                const int* __restrict__ labels,
                                                float* __restrict__ ws,
                                                int N) {
    __shared__ float s_conf[ECE_N_BINS];
    __shared__ float s_acc[ECE_N_BINS];

    const int t = threadIdx.x;
    if (t < ECE_N_BINS) { s_conf[t] = 0.0f; s_acc[t] = 0.0f; }
    __syncthreads();

    const int lane = t & 63;
    const int half = lane >> 5;      // row parity within the pair
    const int s    = lane & 31;      // sublane: column s*4
    const int wavesPerBlock = blockDim.x >> 6;
    const long long waveId  = (long long)blockIdx.x * wavesPerBlock + (t >> 6);
    const long long nWaves  = (long long)gridDim.x * wavesPerBlock;

    const long long nChunks = (long long)N >> 3;          // 8 rows per chunk
    const long long laneOff = (long long)half * 128 + s * 4;

    // pointer strength reduction: advance by nWaves chunks each iteration
    const float* p = sm + (waveId << 10) + laneOff;       // chunk*1024 floats
    const long long pStride = nWaves << 10;

    for (long long c = waveId; c < nChunks; c += nWaves, p += pStride) {
        f32x4 vv[4];
        vv[0] = __builtin_nontemporal_load(reinterpret_cast<const f32x4*>(p));
        vv[1] = __builtin_nontemporal_load(reinterpret_cast<const f32x4*>(p + 256));
        vv[2] = __builtin_nontemporal_load(reinterpret_cast<const f32x4*>(p + 512));
        vv[3] = __builtin_nontemporal_load(reinterpret_cast<const f32x4*>(p + 768));

        float m[4];
        int   ix[4];
        #pragma unroll
        for (int k = 0; k < 4; ++k) {
            float mm = vv[k][0]; int ii = s * 4;
            if (vv[k][1] > mm) { mm = vv[k][1]; ii = s * 4 + 1; }
            if (vv[k][2] > mm) { mm = vv[k][2]; ii = s * 4 + 2; }
            if (vv[k][3] > mm) { mm = vv[k][3]; ii = s * 4 + 3; }
            m[k] = mm; ix[k] = ii;
        }
        // 4 independent butterflies, interleaved so shfl latencies overlap
        #pragma unroll
        for (int off = 1; off < 32; off <<= 1) {
            #pragma unroll
            for (int k = 0; k < 4; ++k) {
                float om = __shfl_xor(m[k], off);
                int   oi = __shfl_xor(ix[k], off);
                bool take = (om > m[k]) || (om == m[k] && oi < ix[k]);
                m[k]  = take ? om : m[k];
                ix[k] = take ? oi : ix[k];
            }
        }
        if (s == 0) {
            const long long row0 = (c << 3) + half;
            #pragma unroll
            for (int k = 0; k < 4; ++k) {
                int b = (int)ceilf(m[k] * 15.0f) - 1;
                b = min(max(b, 0), ECE_N_BINS - 1);
                const float acc = (labels[row0 + 2 * k] == ix[k]) ? 1.0f : 0.0f;
                atomicAdd(&s_conf[b], m[k]);
                atomicAdd(&s_acc[b], acc);
            }
        }
    }

    // tail: rows [nChunks*8, N) as pairs (empty when N % 8 == 0)
    for (long long pair = nChunks * 4 + waveId; pair < ((long long)N + 1) / 2;
         pair += nWaves) {
        const long long row = pair * 2 + half;
        if (row < N) {
            const f32x4 v =
                *reinterpret_cast<const f32x4*>(sm + row * 128 + s * 4);
            float mm = v[0]; int ii = s * 4;
            if (v[1] > mm) { mm = v[1]; ii = s * 4 + 1; }
            if (v[2] > mm) { mm = v[2]; ii = s * 4 + 2; }
            if (v[3] > mm) { mm = v[3]; ii = s * 4 + 3; }
            #pragma unroll
            for (int off = 1; off < 32; off <<= 1) {
                float om = __shfl_xor(mm, off);
                int   oi = __shfl_xor(ii, off);
                if (om > mm || (om == mm && oi < ii)) { mm = om; ii = oi; }
            }
            if (s == 0) {
                int b = (int)ceilf(mm * 15.0f) - 1;
                b = min(max(b, 0), ECE_N_BINS - 1);
                const float acc = (labels[row] == ii) ? 1.0f : 0.0f;
                atomicAdd(&s_conf[b], mm);
                atomicAdd(&s_acc[b], acc);
            }
        }
    }

    __syncthreads();
    if (t < ECE_N_BINS) {
        atomicAdd(&ws[t],              s_conf[t]);
        atomicAdd(&ws[ECE_N_BINS + t], s_acc[t]);
    }
}

// Final: ece = sum_bins |sum_conf - sum_acc| / N
__global__ void ece_final(const float* __restrict__ ws,
                          float* __restrict__ out, int N) {
    if (threadIdx.x == 0 && blockIdx.x == 0) {
        float e = 0.0f;
        #pragma unroll
        for (int i = 0; i < ECE_N_BINS; ++i)
            e += fabsf(ws[i] - ws[ECE_N_BINS + i]);
        out[0] = e / (float)N;
    }
}

extern "C" void kernel_launch(void* const* d_in, const int* in_sizes, int n_in,
                              void* d_out, int out_size, void* d_ws, size_t ws_size,
                              hipStream_t stream) {
    const float* sm     = (const float*)d_in[0];
    const int*   labels = (const int*)d_in[1];
    float*       out    = (float*)d_out;
    float*       ws     = (float*)d_ws;

    const int N = in_sizes[0] / 128;

    ece_zero_ws<<<1, 64, 0, stream>>>(ws);

    const int block = 256;              // 4 waves/block
    const int grid  = 2048;             // 8 blocks/CU x 256 CUs, grid-stride
    ece_main<<<grid, block, 0, stream>>>(sm, labels, ws, N);

    ece_final<<<1, 64, 0, stream>>>(ws, out, N);
}

// Round 4
// 179.113 us; speedup vs baseline: 1.4470x; 1.1468x over previous
//
#include <hip/hip_runtime.h>

#define ECE_N_BINS 15

typedef float f32x4 __attribute__((ext_vector_type(4)));

static __device__ __forceinline__ unsigned umax2(unsigned a, unsigned b) {
    return a > b ? a : b;
}

// Zero the 30-float accumulator in d_ws (harness poisons once, never re-poisons).
__global__ void ece_zero_ws(float* __restrict__ ws) {
    int t = threadIdx.x;
    if (t < 2 * ECE_N_BINS) ws[t] = 0.0f;
}

// One 64-lane wave owns 16 consecutive rows (8 KB) per iteration: lanes 0-31
// handle even rows, 32-63 odd rows; each lane issues 8 independent float4
// loads. Max+argmax are fused into one u32 key per chain:
//   key = (float_bits & ~127) | (127 - col)
// (positive floats are bit-order-monotonic; low 7 bits break ties toward the
// first occurrence). Butterfly = 5 shfl + 5 umax per chain (half the DS ops
// of a (max,idx) pair reduction).
__global__ __launch_bounds__(256) void ece_main(const float* __restrict__ sm,
                                                const int* __restrict__ labels,
                                                float* __restrict__ ws,
                                                int N) {
    __shared__ float s_h[4][2][ECE_N_BINS];   // per-wave histograms

    const int t    = threadIdx.x;
    const int wv   = t >> 6;
    const int lane = t & 63;
    const int half = lane >> 5;          // row parity
    const int s    = lane & 31;          // column group: cols 4s..4s+3
    if (lane < 2 * ECE_N_BINS) ((float*)&s_h[wv][0][0])[lane] = 0.0f;
    __syncthreads();

    const long long waveId = (long long)blockIdx.x * 4 + wv;
    const long long nWaves = (long long)gridDim.x * 4;
    const long long nChunks = (long long)N >> 4;        // 16 rows per chunk

    const float* p = sm + (waveId << 11) + (half << 7) + (s << 2);
    const long long pStride = nWaves << 11;             // floats per stride
    const unsigned base7 = (unsigned)(127 - 4 * s);     // 127 - col base

    for (long long c = waveId; c < nChunks; c += nWaves, p += pStride) {
        // early label prefetch: latency hides under key-build + butterfly
        int lab[8];
        if (s == 0) {
            const long long row0 = (c << 4) + half;
            #pragma unroll
            for (int k = 0; k < 8; ++k) lab[k] = labels[row0 + 2 * k];
        }

        unsigned key[8];
        #pragma unroll
        for (int k = 0; k < 8; ++k) {
            f32x4 v = __builtin_nontemporal_load(
                reinterpret_cast<const f32x4*>(p + k * 256));
            unsigned k0 = (__float_as_uint(v[0]) & 0xFFFFFF80u) | (base7 - 0);
            unsigned k1 = (__float_as_uint(v[1]) & 0xFFFFFF80u) | (base7 - 1);
            unsigned k2 = (__float_as_uint(v[2]) & 0xFFFFFF80u) | (base7 - 2);
            unsigned k3 = (__float_as_uint(v[3]) & 0xFFFFFF80u) | (base7 - 3);
            key[k] = umax2(umax2(k0, k1), umax2(k2, k3));
        }

        // 8 independent butterflies, interleaved (xor<32 stays in each half)
        #pragma unroll
        for (int off = 1; off < 32; off <<= 1) {
            #pragma unroll
            for (int k = 0; k < 8; ++k) {
                unsigned o = (unsigned)__shfl_xor((int)key[k], off);
                key[k] = umax2(key[k], o);
            }
        }

        if (s == 0) {
            #pragma unroll
            for (int k = 0; k < 8; ++k) {
                float conf = __uint_as_float(key[k] & 0xFFFFFF80u);
                int   idx  = 127 - (int)(key[k] & 127u);
                int b = (int)ceilf(conf * 15.0f) - 1;
                b = min(max(b, 0), ECE_N_BINS - 1);
                atomicAdd(&s_h[wv][0][b], conf);
                atomicAdd(&s_h[wv][1][b], (lab[k] == idx) ? 1.0f : 0.0f);
            }
        }
    }

    // tail rows [nChunks*16, N): 2 rows per wave-iter (empty for N%16==0)
    for (long long pr = (nChunks << 4) + 2 * waveId; pr < N; pr += 2 * nWaves) {
        const long long row = pr + half;
        unsigned key = 0;
        if (row < N) {
            const f32x4 v =
                *reinterpret_cast<const f32x4*>(sm + (row << 7) + (s << 2));
            unsigned k0 = (__float_as_uint(v[0]) & 0xFFFFFF80u) | (base7 - 0);
            unsigned k1 = (__float_as_uint(v[1]) & 0xFFFFFF80u) | (base7 - 1);
            unsigned k2 = (__float_as_uint(v[2]) & 0xFFFFFF80u) | (base7 - 2);
            unsigned k3 = (__float_as_uint(v[3]) & 0xFFFFFF80u) | (base7 - 3);
            key = umax2(umax2(k0, k1), umax2(k2, k3));
        }
        #pragma unroll
        for (int off = 1; off < 32; off <<= 1)
            key = umax2(key, (unsigned)__shfl_xor((int)key, off));
        if (s == 0 && row < N) {
            float conf = __uint_as_float(key & 0xFFFFFF80u);
            int   idx  = 127 - (int)(key & 127u);
            int b = (int)ceilf(conf * 15.0f) - 1;
            b = min(max(b, 0), ECE_N_BINS - 1);
            atomicAdd(&s_h[wv][0][b], conf);
            atomicAdd(&s_h[wv][1][b], (labels[row] == idx) ? 1.0f : 0.0f);
        }
    }

    __syncthreads();
    if (t < ECE_N_BINS) {
        float v = s_h[0][0][t] + s_h[1][0][t] + s_h[2][0][t] + s_h[3][0][t];
        atomicAdd(&ws[t], v);
    } else if (t >= 64 && t < 64 + ECE_N_BINS) {
        int b = t - 64;
        float v = s_h[0][1][b] + s_h[1][1][b] + s_h[2][1][b] + s_h[3][1][b];
        atomicAdd(&ws[ECE_N_BINS + b], v);
    }
}

// Final: ece = sum_bins |sum_conf - sum_acc| / N
__global__ void ece_final(const float* __restrict__ ws,
                          float* __restrict__ out, int N) {
    if (threadIdx.x == 0 && blockIdx.x == 0) {
        float e = 0.0f;
        #pragma unroll
        for (int i = 0; i < ECE_N_BINS; ++i)
            e += fabsf(ws[i] - ws[ECE_N_BINS + i]);
        out[0] = e / (float)N;
    }
}

extern "C" void kernel_launch(void* const* d_in, const int* in_sizes, int n_in,
                              void* d_out, int out_size, void* d_ws, size_t ws_size,
                              hipStream_t stream) {
    const float* sm     = (const float*)d_in[0];
    const int*   labels = (const int*)d_in[1];
    float*       out    = (float*)d_out;
    float*       ws     = (float*)d_ws;

    const int N = in_sizes[0] / 128;

    ece_zero_ws<<<1, 64, 0, stream>>>(ws);

    const int block = 256;              // 4 waves/block
    const int grid  = 2048;             // 8 blocks/CU x 256 CUs, grid-stride
    ece_main<<<grid, block, 0, stream>>>(sm, labels, ws, N);

    ece_final<<<1, 64, 0, stream>>>(ws, out, N);
}